// Round 11
// baseline (719.293 us; speedup 1.0000x reference)
//
#include <hip/hip_runtime.h>
#include <math.h>

#define NU_N 200000
#define NS_N 50000
#define E_N  1000000
#define M_N  100000
#define NBU 782    // ceil((NU+1)/256) scan blocks
#define NBS 196    // ceil((NS+1)/256)
#define NUBG 782   // ceil(NU/256) gemm blocks
#define NSBG 196   // ceil(NS/256)
#define NSLICE 512
#define ECH 1954   // ceil(E_N / NSLICE)
#define NTILE 10   // destination sub-tiles per XCD in fill_k (25000/10, 6250/10)

typedef __attribute__((ext_vector_type(8))) short short8;
typedef __attribute__((ext_vector_type(16))) float f32x16;
typedef unsigned short ushort_t;
typedef unsigned int uint_t;

// ---- workspace layout (bytes), ~174 MB ----
static constexpr size_t OFF_AGGU  = 0;             // NU x 128 bf16 (L1: stride 64, L2: 128)
static constexpr size_t OFF_AGGS  = 51200000;      // NS x 128 bf16 (L1: stride 80, L2: 128)
static constexpr size_t OFF_U     = 64000000;      // (NU+1) x 128 bf16 (+zero pad row)
static constexpr size_t OFF_S     = 115200256;     // (NS+1) x 128 bf16
static constexpr size_t OFF_XU16  = 128000512;     // (NU+1) x 64 bf16
static constexpr size_t OFF_XS16  = 153600640;     // (NS+1) x 64 bf16
static constexpr size_t OFF_TBL27 = 160000768;     // 27 x 128 f32
static constexpr size_t OFF_Z1U   = 160014592;     // K=128 swizzled bf16
static constexpr size_t OFF_Z1S   = 160047360;     // K=144 (64 xu | 9 age | 3 gen | 4 pad | 64 self)
static constexpr size_t OFF_Z2U   = 160084224;     // K=256
static constexpr size_t OFF_Z2S   = 160149760;     // K=256
static constexpr size_t OFF_RPU   = 160215296;     // (NU+1) int
static constexpr size_t OFF_RPS   = 161015312;     // (NS+1) int
static constexpr size_t OFF_CSRU  = 161215328;     // (E+8) int
static constexpr size_t OFF_CSRS  = 165215360;     // (E+8) int
static constexpr size_t OFF_HIST  = 169215392;     // histU|histS|curU|curS = 2,000,000
static constexpr size_t OFF_PART  = 173615392;     // 2 x 1024 int

__device__ inline ushort_t f2bf(float f) {
  union { float f; uint_t u; } c; c.f = f;
  uint_t r = (c.u + 0x7FFFu + ((c.u >> 16) & 1u)) >> 16;
  return (ushort_t)r;
}
__device__ inline float u2f(uint_t u) {
  union { uint_t u; float f; } c; c.u = u;
  return c.f;
}
__device__ inline float bf2f(uint_t u) { return u2f(u << 16); }

// ===================== CSR build (XCD-partitioned) =====================
__global__ void hist_k(const int* __restrict__ du, const int* __restrict__ ds,
                       int* __restrict__ histU, int* __restrict__ histS) {
  int xcd = blockIdx.x & 7;
  int slice = blockIdx.x >> 3;
  int uLo = xcd * (NU_N / 8), uHi = uLo + NU_N / 8;
  int sLo = xcd * (NS_N / 8), sHi = sLo + NS_N / 8;
  int e0 = slice * ECH;
  int e1 = min(E_N, e0 + ECH);
  for (int e = e0 + (int)threadIdx.x; e < e1; e += 256) {
    int u = du[e];
    if (u >= uLo && u < uHi) atomicAdd(&histU[u], 1);
    int s = ds[e];
    if (s >= sLo && s < sHi) atomicAdd(&histS[s], 1);
  }
}

__global__ void scan1_k(const int* __restrict__ histU, const int* __restrict__ histS,
                        int* __restrict__ rpU, int* __restrict__ rpS,
                        int* __restrict__ part) {
  __shared__ int s[256];
  int blk = blockIdx.x;
  const int* hist; int n; int* rowptr; int* pp;
  if (blk < NBU) { hist = histU; n = NU_N + 1; rowptr = rpU; pp = part; }
  else { blk -= NBU; hist = histS; n = NS_N + 1; rowptr = rpS; pp = part + 1024; }
  int t = threadIdx.x;
  int idx = blk * 256 + t;
  int v = (idx > 0 && idx < n) ? hist[idx - 1] : 0;
  s[t] = v;
  __syncthreads();
  for (int off = 1; off < 256; off <<= 1) {
    int x = (t >= off) ? s[t - off] : 0;
    __syncthreads();
    s[t] += x;
    __syncthreads();
  }
  if (idx < n) rowptr[idx] = s[t];
  if (t == 255) pp[blk] = s[255];
}

__global__ void scan2_k(int* __restrict__ part) {
  __shared__ int s[1024];
  int* pp = part + blockIdx.x * 1024;
  int nb = (blockIdx.x == 0) ? NBU : NBS;
  int t = threadIdx.x;
  int v = (t < nb) ? pp[t] : 0;
  s[t] = v;
  __syncthreads();
  for (int off = 1; off < 1024; off <<= 1) {
    int x = (t >= off) ? s[t - off] : 0;
    __syncthreads();
    s[t] += x;
    __syncthreads();
  }
  if (t < nb) pp[t] = s[t] - v;  // exclusive
}

__global__ void scan3_k(int* __restrict__ rpU, int* __restrict__ rpS,
                        const int* __restrict__ part) {
  int blk = blockIdx.x;
  int* rowptr; int n; const int* pp;
  if (blk < NBU) { rowptr = rpU; n = NU_N + 1; pp = part; }
  else { blk -= NBU; rowptr = rpS; n = NS_N + 1; pp = part + 1024; }
  int idx = blk * 256 + threadIdx.x;
  if (idx < n) rowptr[idx] += pp[blk];
}

// fill: XCD-partitioned + destination-tiled. Each block loops NTILE dst tiles
// over its L1/L2-resident edge chunk; per tile the live csr region (~100 KB/XCD)
// stays L2-resident -> each csr line evicted once, fully written.
__global__ void fill_k(const int* __restrict__ su, const int* __restrict__ ds,
                       const int* __restrict__ ss, const int* __restrict__ du,
                       const int* __restrict__ rpU, const int* __restrict__ rpS,
                       int* __restrict__ curU, int* __restrict__ curS,
                       int* __restrict__ csrU, int* __restrict__ csrS) {
  int xcd = blockIdx.x & 7;
  int slice = blockIdx.x >> 3;
  int uBase = xcd * (NU_N / 8);
  int sBase = xcd * (NS_N / 8);
  int e0 = slice * ECH;
  int e1 = min(E_N, e0 + ECH);
#pragma unroll 1
  for (int t = 0; t < NTILE; ++t) {
    int ut0 = uBase + t * (NU_N / 8 / NTILE), ut1 = ut0 + NU_N / 8 / NTILE;
    int st0 = sBase + t * (NS_N / 8 / NTILE), st1 = st0 + NS_N / 8 / NTILE;
    for (int e = e0 + (int)threadIdx.x; e < e1; e += 256) {
      int u = du[e];
      if (u >= ut0 && u < ut1) {
        int p = atomicAdd(&curU[u], 1);
        csrU[rpU[u] + p] = ss[e];
      }
      int s = ds[e];
      if (s >= st0 && s < st1) {
        int q = atomicAdd(&curS[s], 1);
        csrS[rpS[s] + q] = su[e];
      }
    }
  }
}

// ===================== merged prep: bf16 feats + pads + tbl27 + weight swizzles ====
__global__ void prep_all_k(const float* __restrict__ xu, const float* __restrict__ xs,
                           const int* __restrict__ x1, const float* __restrict__ age,
                           const float* __restrict__ gen,
                           const float* __restrict__ W1ul, const float* __restrict__ W1ur,
                           const float* __restrict__ W1sl, const float* __restrict__ W1sr,
                           const float* __restrict__ W2ul, const float* __restrict__ W2ur,
                           const float* __restrict__ W2sl, const float* __restrict__ W2sr,
                           ushort_t* __restrict__ xu16, ushort_t* __restrict__ xs16,
                           ushort_t* __restrict__ ub, ushort_t* __restrict__ sb,
                           float* __restrict__ tbl27,
                           ushort_t* __restrict__ z1u, ushort_t* __restrict__ z1s,
                           ushort_t* __restrict__ z2u, ushort_t* __restrict__ z2s) {
  int t = blockIdx.x * 256 + threadIdx.x;
  if (t < 4000000) {  // xu16 (3.2M float4s) then xs16 (800k)
    const float* src = (t < 3200000) ? xu : xs;
    ushort_t* dst = (t < 3200000) ? xu16 : xs16;
    int i = (t < 3200000) ? t : t - 3200000;
    float4 v = ((const float4*)src)[i];
    uint2 o;
    o.x = (uint_t)f2bf(v.x) | ((uint_t)f2bf(v.y) << 16);
    o.y = (uint_t)f2bf(v.z) | ((uint_t)f2bf(v.w) << 16);
    ((uint2*)dst)[i] = o;
  } else if (t < 4000096) {  // zero pad rows
    int t3 = t - 4000000;
    uint2 z; z.x = 0u; z.y = 0u;
    if (t3 < 16)       ((uint2*)xu16)[NU_N * 16 + t3] = z;
    else if (t3 < 32)  ((uint2*)xs16)[NS_N * 16 + (t3 - 16)] = z;
    else if (t3 < 64)  ((uint2*)ub)[NU_N * 32 + (t3 - 32)] = z;
    else               ((uint2*)sb)[NS_N * 32 + (t3 - 64)] = z;
  } else if (t < 4003552) {  // tbl27: 27 x 128
    int i = t - 4000096;
    int tt = i >> 7, j = i & 127;
    int a = tt / 3, g = tt % 3;
    float acc = 0.f;
    for (int k = 0; k < 32; ++k) acc += age[a * 32 + k] * W1ur[k * 128 + j];
    for (int k = 0; k < 32; ++k) acc += gen[g * 32 + k] * W1ur[(32 + k) * 128 + j];
    tbl27[i] = acc;
  } else if (t < 4019936) {  // z1u: K=128 (W1ul 64 | W1ur[64:128])
    int i = t - 4003552;
    int j = i & 7, lane = (i >> 3) & 63, rest = i >> 9;
    int kt = rest % 8, ct = rest / 8;
    int k = kt * 16 + ((lane >> 5) << 3) + j;
    int n = ct * 32 + (lane & 31);
    float v = (k < 64) ? W1ul[k * 128 + n] : W1ur[k * 128 + n];
    z1u[i] = f2bf(v);
  } else if (t < 4038368) {  // z1s: K=144 (W1sl[64:128] | ageW 9 | genW 3 | 0 x4 | W1sr 64)
    int i = t - 4019936;
    int j = i & 7, lane = (i >> 3) & 63, rest = i >> 9;
    int kt = rest % 9, ct = rest / 9;
    int k = kt * 16 + ((lane >> 5) << 3) + j;
    int n = ct * 32 + (lane & 31);
    float v;
    if (k < 64) v = W1sl[(64 + k) * 128 + n];
    else if (k < 73) {
      int a = k - 64; v = 0.f;
      for (int kk = 0; kk < 32; ++kk) v += age[a * 32 + kk] * W1sl[kk * 128 + n];
    } else if (k < 76) {
      int g = k - 73; v = 0.f;
      for (int kk = 0; kk < 32; ++kk) v += gen[g * 32 + kk] * W1sl[(32 + kk) * 128 + n];
    } else if (k < 80) v = 0.f;
    else v = W1sr[(k - 80) * 128 + n];
    z1s[i] = f2bf(v);
  } else if (t < 4103904) {  // z2u then z2s: K=256
    int i = t - 4038368;
    const float *Wl, *Wr; ushort_t* dst;
    if (i < 32768) { Wl = W2ul; Wr = W2ur; dst = z2u; }
    else { Wl = W2sl; Wr = W2sr; dst = z2s; i -= 32768; }
    int j = i & 7, lane = (i >> 3) & 63, rest = i >> 9;
    int kt = rest % 16, ct = rest / 16;
    int k = kt * 16 + ((lane >> 5) << 3) + j;
    int n = ct * 32 + (lane & 31);
    float v = (k < 128) ? Wl[k * 128 + n] : Wr[(k - 128) * 128 + n];
    dst[i] = f2bf(v);
  }
}

// ===================== gather cores (body/tail + csr prefetch) =====================
#define ACC8(V)                                              \
  acc[0] += bf2f(V.x); acc[1] += u2f(V.x & 0xffff0000u);     \
  acc[2] += bf2f(V.y); acc[3] += u2f(V.y & 0xffff0000u);     \
  acc[4] += bf2f(V.z); acc[5] += u2f(V.z & 0xffff0000u);     \
  acc[6] += bf2f(V.w); acc[7] += u2f(V.w & 0xffff0000u);

// 128-bf16 rows (256 B): 4 neighbor groups x 16 lanes, 8 rows/iter in flight.
__device__ inline void gmean128(int b, int e, const int* __restrict__ csr, int zrow,
                                const ushort_t* __restrict__ src,
                                ushort_t* __restrict__ dst, int lane) {
  int n = e - b;
  int g = lane >> 4, c = lane & 15;
  const uint4* s4 = (const uint4*)src;
  float acc[8];
#pragma unroll
  for (int k = 0; k < 8; ++k) acc[k] = 0.f;
  int nb = n & ~7;
  if (nb) {
    int p0 = b + g, p1 = p0 + 4;
    int j0 = csr[p0], j1 = csr[p1];
    for (int base = 8;; base += 8) {
      uint4 v0 = s4[(size_t)j0 * 16 + c];
      uint4 v1 = s4[(size_t)j1 * 16 + c];
      bool more = base < nb;
      if (more) { j0 = csr[p0 + base]; j1 = csr[p1 + base]; }
      ACC8(v0); ACC8(v1);
      if (!more) break;
    }
  }
  if (nb < n) {  // masked tail (csr padded +8 -> reads safe)
    int p0 = b + nb + g, p1 = p0 + 4;
    int j0 = csr[p0]; j0 = (p0 < e) ? j0 : zrow;
    int j1 = csr[p1]; j1 = (p1 < e) ? j1 : zrow;
    uint4 v0 = s4[(size_t)j0 * 16 + c];
    uint4 v1 = s4[(size_t)j1 * 16 + c];
    ACC8(v0); ACC8(v1);
  }
#pragma unroll
  for (int k = 0; k < 8; ++k) acc[k] += __shfl_down(acc[k], 32);
#pragma unroll
  for (int k = 0; k < 8; ++k) acc[k] += __shfl_down(acc[k], 16);
  if (lane < 16) {
    float inv = 1.0f / fmaxf((float)n, 1.0f);
    uint4 o;
    o.x = (uint_t)f2bf(acc[0] * inv) | ((uint_t)f2bf(acc[1] * inv) << 16);
    o.y = (uint_t)f2bf(acc[2] * inv) | ((uint_t)f2bf(acc[3] * inv) << 16);
    o.z = (uint_t)f2bf(acc[4] * inv) | ((uint_t)f2bf(acc[5] * inv) << 16);
    o.w = (uint_t)f2bf(acc[6] * inv) | ((uint_t)f2bf(acc[7] * inv) << 16);
    ((uint4*)dst)[lane] = o;
  }
}

// 64-bf16 rows (128 B): 8 neighbor groups x 8 lanes, 8 rows/iter.
__device__ inline void gmean64(int b, int e, const int* __restrict__ csr, int zrow,
                               const ushort_t* __restrict__ src,
                               ushort_t* __restrict__ dst, int lane) {
  int n = e - b;
  int g = lane >> 3, c = lane & 7;
  const uint4* s4 = (const uint4*)src;
  float acc[8];
#pragma unroll
  for (int k = 0; k < 8; ++k) acc[k] = 0.f;
  int nb = n & ~7;
  if (nb) {
    int p = b + g;
    int j = csr[p];
    for (int base = 8;; base += 8) {
      uint4 v = s4[(size_t)j * 8 + c];
      bool more = base < nb;
      if (more) j = csr[p + base];
      ACC8(v);
      if (!more) break;
    }
  }
  if (nb < n) {
    int p = b + nb + g;
    int j = csr[p]; j = (p < e) ? j : zrow;
    uint4 v = s4[(size_t)j * 8 + c];
    ACC8(v);
  }
#pragma unroll
  for (int k = 0; k < 8; ++k) acc[k] += __shfl_down(acc[k], 32);
#pragma unroll
  for (int k = 0; k < 8; ++k) acc[k] += __shfl_down(acc[k], 16);
#pragma unroll
  for (int k = 0; k < 8; ++k) acc[k] += __shfl_down(acc[k], 8);
  if (lane < 8) {
    float inv = 1.0f / fmaxf((float)n, 1.0f);
    uint4 o;
    o.x = (uint_t)f2bf(acc[0] * inv) | ((uint_t)f2bf(acc[1] * inv) << 16);
    o.y = (uint_t)f2bf(acc[2] * inv) | ((uint_t)f2bf(acc[3] * inv) << 16);
    o.z = (uint_t)f2bf(acc[4] * inv) | ((uint_t)f2bf(acc[5] * inv) << 16);
    o.w = (uint_t)f2bf(acc[6] * inv) | ((uint_t)f2bf(acc[7] * inv) << 16);
    ((uint4*)dst)[lane] = o;
  }
}

// Seller variant: 64-d mean + register-accumulated age/gen neighbor counts.
// Lane channel c accumulates cA = #(age==c) (bins 0..7) and
// cB = c==0 ? #(age==8) : c<=3 ? #(gen==c-1) : 0 (bins 8..11). No atomics.
__device__ inline void gmean64_cnt(int b, int e, const int* __restrict__ csr, int zrow,
                                   const ushort_t* __restrict__ src,
                                   const int2* __restrict__ x1p,
                                   ushort_t* __restrict__ dst, int lane) {
  int n = e - b;
  int g = lane >> 3, c = lane & 7;
  const uint4* s4 = (const uint4*)src;
  float acc[8];
  float cA = 0.f, cB = 0.f;
#pragma unroll
  for (int k = 0; k < 8; ++k) acc[k] = 0.f;
  int nb = n & ~7;
  if (nb) {
    int p = b + g;
    int j = csr[p];
    int2 ag = x1p[j];
    for (int base = 8;; base += 8) {
      uint4 v = s4[(size_t)j * 8 + c];
      bool more = base < nb;
      int jn = 0;
      if (more) jn = csr[p + base];
      ACC8(v);
      cA += (ag.x == c) ? 1.f : 0.f;
      if (c == 0) cB += (ag.x == 8) ? 1.f : 0.f;
      else if (c <= 3) cB += (ag.y == c - 1) ? 1.f : 0.f;
      if (!more) break;
      j = jn;
      ag = x1p[j];
    }
  }
  if (nb < n) {
    int p = b + nb + g;
    bool vb = p < e;
    int j = csr[p];
    int jx = vb ? j : 0;          // safe x1 index
    int2 ag = x1p[jx];
    j = vb ? j : zrow;
    uint4 v = s4[(size_t)j * 8 + c];
    ACC8(v);
    if (vb) {
      cA += (ag.x == c) ? 1.f : 0.f;
      if (c == 0) cB += (ag.x == 8) ? 1.f : 0.f;
      else if (c <= 3) cB += (ag.y == c - 1) ? 1.f : 0.f;
    }
  }
#pragma unroll
  for (int k = 0; k < 8; ++k) acc[k] += __shfl_down(acc[k], 32);
  cA += __shfl_down(cA, 32); cB += __shfl_down(cB, 32);
#pragma unroll
  for (int k = 0; k < 8; ++k) acc[k] += __shfl_down(acc[k], 16);
  cA += __shfl_down(cA, 16); cB += __shfl_down(cB, 16);
#pragma unroll
  for (int k = 0; k < 8; ++k) acc[k] += __shfl_down(acc[k], 8);
  cA += __shfl_down(cA, 8); cB += __shfl_down(cB, 8);
  float inv = 1.0f / fmaxf((float)n, 1.0f);
  // bins: i<8 -> cA@lane i ; i in 8..11 -> cB@lane i-8. Lanes 8..13 write pairs.
  int cp = lane - 8;                       // pair index for lanes 8..15
  int i0 = 2 * cp, i1 = 2 * cp + 1;
  float sA0 = __shfl(cA, i0 & 7), sA1 = __shfl(cA, i1 & 7);
  float sB0 = __shfl(cB, (i0 - 8) & 3), sB1 = __shfl(cB, (i1 - 8) & 3);
  float v0 = (i0 < 8) ? sA0 : sB0;
  float v1 = (i1 < 8) ? sA1 : sB1;
  if (lane < 8) {
    uint4 o;
    o.x = (uint_t)f2bf(acc[0] * inv) | ((uint_t)f2bf(acc[1] * inv) << 16);
    o.y = (uint_t)f2bf(acc[2] * inv) | ((uint_t)f2bf(acc[3] * inv) << 16);
    o.z = (uint_t)f2bf(acc[4] * inv) | ((uint_t)f2bf(acc[5] * inv) << 16);
    o.w = (uint_t)f2bf(acc[6] * inv) | ((uint_t)f2bf(acc[7] * inv) << 16);
    ((uint4*)dst)[lane] = o;
  } else if (lane < 16) {
    float b0v = (cp < 6) ? v0 * inv : 0.f;   // lanes 14,15 -> zero pad (pos 76..79)
    float b1v = (cp < 6) ? v1 * inv : 0.f;
    ((uint_t*)dst)[32 + cp] = (uint_t)f2bf(b0v) | ((uint_t)f2bf(b1v) << 16);
  }
}

// layer 1: users mean xs16 (64-d); sellers mean xu16 (64-d) + 12 count feats -> 80-d
__global__ void gather1_k(const int* __restrict__ rpU, const int* __restrict__ csrU,
                          const ushort_t* __restrict__ xs16,
                          const int* __restrict__ rpS, const int* __restrict__ csrS,
                          const ushort_t* __restrict__ xu16,
                          const int* __restrict__ x1,
                          ushort_t* __restrict__ aggU, ushort_t* __restrict__ aggS) {
  int w = (blockIdx.x * blockDim.x + threadIdx.x) >> 6;
  int lane = threadIdx.x & 63;
  if (w < NU_N) {
    gmean64(rpU[w], rpU[w + 1], csrU, NS_N, xs16, aggU + (size_t)w * 64, lane);
  } else if (w < NU_N + NS_N) {
    int r = w - NU_N;
    gmean64_cnt(rpS[r], rpS[r + 1], csrS, NU_N, xu16, (const int2*)x1,
                aggS + (size_t)r * 80, lane);
  }
}

// layer 2: users mean s1 rows; sellers mean u1 rows (both 128-d)
__global__ void gather2_k(const int* __restrict__ rpU, const int* __restrict__ csrU,
                          const ushort_t* __restrict__ s1,
                          const int* __restrict__ rpS, const int* __restrict__ csrS,
                          const ushort_t* __restrict__ u1,
                          ushort_t* __restrict__ aggU, ushort_t* __restrict__ aggS) {
  int w = (blockIdx.x * blockDim.x + threadIdx.x) >> 6;
  int lane = threadIdx.x & 63;
  if (w < NU_N) {
    gmean128(rpU[w], rpU[w + 1], csrU, NS_N, s1, aggU + (size_t)w * 128, lane);
  } else if (w < NU_N + NS_N) {
    int r = w - NU_N;
    gmean128(rpS[r], rpS[r + 1], csrS, NU_N, u1, aggS + (size_t)r * 128, lane);
  }
}

// ===================== MFMA row-GEMM core (bf16 in, bf16 out) =====================
template <int KM, int KS, int SSTR, bool TBL>
__device__ __forceinline__ void gemm_core(
    short* sW, int bid, int nrows, const ushort_t* __restrict__ agg,
    const ushort_t* self, const ushort_t* __restrict__ wswz,
    const float* __restrict__ bias, const float* __restrict__ tbl27,
    const int* __restrict__ x1, ushort_t* out) {
  constexpr int K = KM + KS;
  constexpr int NKT = K / 16;
  {
    const uint4* g4 = (const uint4*)wswz;
    uint4* s4 = (uint4*)sW;
    for (int i = threadIdx.x; i < K * 16; i += 256) s4[i] = g4[i];
  }
  __syncthreads();

  int wave = threadIdx.x >> 6, lane = threadIdx.x & 63;
  int r0 = bid * 256 + wave * 64;
  int qk = (lane >> 5) << 3;

  int ra = r0 + (lane & 31), rb = ra + 32;
  int rac = (ra < nrows) ? ra : 0, rbc = (rb < nrows) ? rb : 0;

  f32x16 acc[2][4];
#pragma unroll
  for (int rt = 0; rt < 2; ++rt)
#pragma unroll
    for (int ct = 0; ct < 4; ++ct) acc[rt][ct] = (f32x16)0.0f;

  const short8* sWv = (const short8*)sW;

#pragma unroll
  for (int kt = 0; kt < NKT; ++kt) {
    int k0 = kt * 16 + qk;
    short8 af, bf;
    if (kt * 16 < KM) {
      af = *((const short8*)(agg + (size_t)rac * KM + k0));
      bf = *((const short8*)(agg + (size_t)rbc * KM + k0));
    } else {
      af = *((const short8*)(self + (size_t)rac * SSTR + (k0 - KM)));
      bf = *((const short8*)(self + (size_t)rbc * SSTR + (k0 - KM)));
    }
#pragma unroll
    for (int ct = 0; ct < 4; ++ct) {
      short8 wf = sWv[(ct * NKT + kt) * 64 + lane];
      acc[0][ct] = __builtin_amdgcn_mfma_f32_32x32x16_bf16(af, wf, acc[0][ct], 0, 0, 0);
      acc[1][ct] = __builtin_amdgcn_mfma_f32_32x32x16_bf16(bf, wf, acc[1][ct], 0, 0, 0);
    }
  }

  int nloc = lane & 31;
  float bn[4];
#pragma unroll
  for (int ct = 0; ct < 4; ++ct) bn[ct] = bias[ct * 32 + nloc];
  int rowq = 4 * (lane >> 5);
#pragma unroll
  for (int rt = 0; rt < 2; ++rt) {
#pragma unroll
    for (int reg = 0; reg < 16; ++reg) {
      int row = r0 + rt * 32 + (reg & 3) + 8 * (reg >> 2) + rowq;
      if (row < nrows) {
        const float* tp = nullptr;
        if (TBL) {
          int a = x1[2 * row], g = x1[2 * row + 1];
          tp = tbl27 + (a * 3 + g) * 128 + nloc;
        }
#pragma unroll
        for (int ct = 0; ct < 4; ++ct) {
          float v = acc[rt][ct][reg] + bn[ct];
          if (TBL) v += tp[ct * 32];
          out[(size_t)row * 128 + ct * 32 + nloc] = f2bf(fmaxf(v, 0.0f));
        }
      }
    }
  }
}

// merged layer-1 GEMM: blocks [0,NUBG) user (K=128), [NUBG,+NSBG) seller (K=144)
__global__ __launch_bounds__(256, 2) void gemm1_k(
    const ushort_t* __restrict__ aggU, const ushort_t* __restrict__ aggS,
    const ushort_t* __restrict__ xu16, const ushort_t* __restrict__ xs16,
    const ushort_t* __restrict__ z1u, const ushort_t* __restrict__ z1s,
    const float* __restrict__ b1u, const float* __restrict__ b1s,
    const float* __restrict__ tbl27, const int* __restrict__ x1,
    ushort_t* __restrict__ ub, ushort_t* __restrict__ sb) {
  extern __shared__ short smem[];
  if (blockIdx.x < NUBG)
    gemm_core<64, 64, 64, true>(smem, blockIdx.x, NU_N, aggU, xu16, z1u, b1u, tbl27, x1, ub);
  else
    gemm_core<80, 64, 64, false>(smem, blockIdx.x - NUBG, NS_N, aggS, xs16, z1s, b1s,
                                 nullptr, nullptr, sb);
}

// merged layer-2 GEMM (both K=256, in-place)
__global__ __launch_bounds__(256, 2) void gemm2_k(
    const ushort_t* __restrict__ aggU, const ushort_t* __restrict__ aggS,
    const ushort_t* __restrict__ z2u, const ushort_t* __restrict__ z2s,
    const float* __restrict__ b2u, const float* __restrict__ b2s,
    ushort_t* ub, ushort_t* sb) {
  extern __shared__ short smem[];
  if (blockIdx.x < NUBG)
    gemm_core<128, 128, 128, false>(smem, blockIdx.x, NU_N, aggU, ub, z2u, b2u,
                                    nullptr, nullptr, ub);
  else
    gemm_core<128, 128, 128, false>(smem, blockIdx.x - NUBG, NS_N, aggS, sb, z2s, b2s,
                                    nullptr, nullptr, sb);
}

// ===================== final =====================
__global__ void final_k(const ushort_t* __restrict__ u2, const ushort_t* __restrict__ s2,
                        const int* __restrict__ mu, const int* __restrict__ ms,
                        const float* __restrict__ lw, const float* __restrict__ lb,
                        float* __restrict__ out) {
  int w = (blockIdx.x * blockDim.x + threadIdx.x) >> 6;
  int lane = threadIdx.x & 63;
  if (w >= M_N) return;
  int iu = mu[w], is = ms[w];
  uint_t a = ((const uint_t*)(u2 + (size_t)iu * 128))[lane];
  uint_t b = ((const uint_t*)(s2 + (size_t)is * 128))[lane];
  float p = bf2f(a & 0xffffu) * lw[2 * lane] + bf2f(a >> 16) * lw[2 * lane + 1]
          + bf2f(b & 0xffffu) * lw[128 + 2 * lane] + bf2f(b >> 16) * lw[129 + 2 * lane];
#pragma unroll
  for (int off = 32; off > 0; off >>= 1) p += __shfl_down(p, off, 64);
  if (lane == 0) out[w] = 1.0f / (1.0f + expf(-(p + lb[0])));
}

extern "C" void kernel_launch(void* const* d_in, const int* in_sizes, int n_in,
                              void* d_out, int out_size, void* d_ws, size_t ws_size,
                              hipStream_t stream) {
  const float* xu   = (const float*)d_in[0];
  const float* xs   = (const float*)d_in[1];
  const int*   x1   = (const int*)d_in[2];
  const int*   su   = (const int*)d_in[3];
  const int*   ds   = (const int*)d_in[4];
  const int*   ss   = (const int*)d_in[5];
  const int*   du   = (const int*)d_in[6];
  const int*   mu   = (const int*)d_in[7];
  const int*   ms   = (const int*)d_in[8];
  const float* age  = (const float*)d_in[9];
  const float* gen  = (const float*)d_in[10];
  const float* W1ul = (const float*)d_in[11];
  const float* W1ur = (const float*)d_in[12];
  const float* b1u  = (const float*)d_in[13];
  const float* W1sl = (const float*)d_in[14];
  const float* W1sr = (const float*)d_in[15];
  const float* b1s  = (const float*)d_in[16];
  const float* W2ul = (const float*)d_in[17];
  const float* W2ur = (const float*)d_in[18];
  const float* b2u  = (const float*)d_in[19];
  const float* W2sl = (const float*)d_in[20];
  const float* W2sr = (const float*)d_in[21];
  const float* b2s  = (const float*)d_in[22];
  const float* lw   = (const float*)d_in[23];
  const float* lb   = (const float*)d_in[24];

  char* w = (char*)d_ws;
  ushort_t* aggU = (ushort_t*)(w + OFF_AGGU);
  ushort_t* aggS = (ushort_t*)(w + OFF_AGGS);
  ushort_t* ub   = (ushort_t*)(w + OFF_U);
  ushort_t* sb   = (ushort_t*)(w + OFF_S);
  ushort_t* xu16 = (ushort_t*)(w + OFF_XU16);
  ushort_t* xs16 = (ushort_t*)(w + OFF_XS16);
  float* tbl27   = (float*)(w + OFF_TBL27);
  ushort_t* z1u  = (ushort_t*)(w + OFF_Z1U);
  ushort_t* z1s  = (ushort_t*)(w + OFF_Z1S);
  ushort_t* z2u  = (ushort_t*)(w + OFF_Z2U);
  ushort_t* z2s  = (ushort_t*)(w + OFF_Z2S);
  int* rpU    = (int*)(w + OFF_RPU);
  int* rpS    = (int*)(w + OFF_RPS);
  int* csrU   = (int*)(w + OFF_CSRU);
  int* csrS   = (int*)(w + OFF_CSRS);
  int* histU  = (int*)(w + OFF_HIST);
  int* histS  = (int*)(w + OFF_HIST + 800000);
  int* curU   = (int*)(w + OFF_HIST + 1000000);
  int* curS   = (int*)(w + OFF_HIST + 1800000);
  int* part   = (int*)(w + OFF_PART);
  float* out = (float*)d_out;

  // ---- CSR build (XCD-partitioned, destination-tiled fill) + prep ----
  hipMemsetAsync(w + OFF_HIST, 0, 2000000, stream);  // histU|histS|curU|curS
  hist_k<<<8 * NSLICE, 256, 0, stream>>>(du, ds, histU, histS);
  scan1_k<<<NBU + NBS, 256, 0, stream>>>(histU, histS, rpU, rpS, part);
  scan2_k<<<2, 1024, 0, stream>>>(part);
  scan3_k<<<NBU + NBS, 256, 0, stream>>>(rpU, rpS, part);
  fill_k<<<8 * NSLICE, 256, 0, stream>>>(su, ds, ss, du, rpU, rpS,
                                         curU, curS, csrU, csrS);
  prep_all_k<<<16031, 256, 0, stream>>>(xu, xs, x1, age, gen,
                                        W1ul, W1ur, W1sl, W1sr, W2ul, W2ur, W2sl, W2sr,
                                        xu16, xs16, ub, sb, tbl27, z1u, z1s, z2u, z2s);

  // ---- layer 1 ----
  gather1_k<<<(NU_N + NS_N) / 4, 256, 0, stream>>>(rpU, csrU, xs16, rpS, csrS, xu16,
                                                   x1, aggU, aggS);
  gemm1_k<<<NUBG + NSBG, 256, 144 * 128 * 2, stream>>>(aggU, aggS, xu16, xs16, z1u, z1s,
                                                       b1u, b1s, tbl27, x1, ub, sb);

  // ---- layer 2 ----
  gather2_k<<<(NU_N + NS_N) / 4, 256, 0, stream>>>(rpU, csrU, sb, rpS, csrS, ub,
                                                   aggU, aggS);
  gemm2_k<<<NUBG + NSBG, 256, 256 * 128 * 2, stream>>>(aggU, aggS, z2u, z2s,
                                                       b2u, b2s, ub, sb);

  // ---- final linear + sigmoid ----
  final_k<<<(M_N * 64 + 255) / 256, 256, 0, stream>>>(ub, sb, mu, ms, lw, lb, out);
}